// Round 3
// baseline (152.881 us; speedup 1.0000x reference)
//
#include <hip/hip_runtime.h>
#include <hip/hip_bf16.h>
#include <math.h>

#define OBS_DIM 256
#define FEAT 128
#define HID 64
#define N_OPT 8
#define ACT_N 18
#define BATCH 32768

typedef unsigned short u16;
typedef unsigned int u32;
typedef __attribute__((ext_vector_type(8))) short short8;
typedef __attribute__((ext_vector_type(4))) float f32x4;
typedef __attribute__((ext_vector_type(4))) u16 u16x4;

#define MFMA(a, b, c) __builtin_amdgcn_mfma_f32_16x16x32_bf16((a), (b), (c), 0, 0, 0)

// XOR swizzle (T2): spread same-column ds_read_b128 frags across 8 16B slots.
#define SWZ(row, off) ((off) ^ (((row) & 7) << 4))

// ---- ws layout (bytes): bf16 weights only ----
#define WS_FW1 0                        // [64][256]
#define WS_FW2 (WS_FW1 + 64*256*2)      // [128][64]
#define WS_PW  (WS_FW2 + 128*64*2)      // [16][128] zero-padded rows 8..15
#define WS_TW  (WS_PW  + 16*128*2)      // [16][128] zero-padded
#define WS_OW1 (WS_TW  + 16*128*2)      // [8][64][128]
#define WS_OW2 (WS_OW1 + 8*64*128*2)    // [8][32][64] zero-padded rows 18..31

__device__ __forceinline__ u16 bf(float x) {  // RNE f32->bf16
    u32 u = __float_as_uint(x);
    return (u16)((u + 0x7fffu + ((u >> 16) & 1u)) >> 16);
}

// ---------------------------------------------------------------------------
// K0: weight conversion fp32 -> bf16 (+ zero padding). Re-run every launch
// (ws is re-poisoned by the harness).
// ---------------------------------------------------------------------------
__global__ __launch_bounds__(256) void k_prep(
    const float* __restrict__ fW1, const float* __restrict__ fW2,
    const float* __restrict__ pW,  const float* __restrict__ tW,
    const float* __restrict__ oW1, const float* __restrict__ oW2,
    u16* __restrict__ fW1b, u16* __restrict__ fW2b,
    u16* __restrict__ pWb,  u16* __restrict__ tWb,
    u16* __restrict__ oW1b, u16* __restrict__ oW2b)
{
    int gid = blockIdx.x * 256 + threadIdx.x;
    int stride = gridDim.x * 256;
    for (int i = gid; i < 64 * 256; i += stride) fW1b[i] = bf(fW1[i]);
    for (int i = gid; i < 128 * 64; i += stride) fW2b[i] = bf(fW2[i]);
    for (int i = gid; i < 16 * 128; i += stride) {
        int r = i >> 7;
        pWb[i] = (r < 8) ? bf(pW[i]) : (u16)0;
        tWb[i] = (r < 8) ? bf(tW[i]) : (u16)0;
    }
    for (int i = gid; i < 8 * 64 * 128; i += stride) oW1b[i] = bf(oW1[i]);
    for (int i = gid; i < 8 * 32 * 64; i += stride) {
        int o = i >> 11, a = (i >> 6) & 31, e = i & 63;
        oW2b[i] = (a < ACT_N) ? bf(oW2[(o * ACT_N + a) * 64 + e]) : (u16)0;
    }
}

// ---------------------------------------------------------------------------
// K1: fully fused. 64 rows/block, 4 waves (each owns a 16-row band).
//   trunk L1: [64,256]@[256,64]   (8K x 4N)
//   trunk L2: [64,64]@[64,128]    (2K x 8N)
//   heads:    [64,128]@[128,16]x2, col=opt via shfl
//   expert L1: for all 8 options  (4K x 4N each), select rows by opt
//   expert L2: for all 8 options  (2K x 2N each), select rows by opt
//   log-softmax over 18 logits, gather act.
// Weights (~216 KB total) are L2-resident; only obs streams from HBM.
// LDS union keeps the block at ~40 KB -> 3 blocks/CU.
// ---------------------------------------------------------------------------
__global__ __launch_bounds__(256) void k_fused(
    const float* __restrict__ obs, const int* __restrict__ opt,
    const int* __restrict__ act,
    const u16* __restrict__ fW1b, const float* __restrict__ fb1,
    const u16* __restrict__ fW2b, const float* __restrict__ fb2,
    const u16* __restrict__ pWb,  const float* __restrict__ pb,
    const u16* __restrict__ tWb,  const float* __restrict__ tb,
    const u16* __restrict__ oW1b, const float* __restrict__ ob1,
    const u16* __restrict__ oW2b, const float* __restrict__ ob2,
    float* __restrict__ out)
{
    __shared__ char lmem[40 * 1024];
    __shared__ int lOpt[64];
    char* lA = lmem;              // 64x256 bf16 swz (stage -> trunk L1)
    char* lH = lmem + 32 * 1024;  // 64x64  bf16 swz (L1 -> L2)
    char* lS = lmem;              // 64x128 bf16 swz (aliases dead lA)
    char* lE = lmem + 16 * 1024;  // 64x64  bf16 swz (expert hidden)
    float* lL = (float*)(lmem + 24 * 1024);  // 64x19 f32 logits

    const int tid = threadIdx.x;
    const int tile = blockIdx.x;
    const int w = tid >> 6, l = tid & 63, lg = l >> 4, lc = l & 15;
    const int arow = 16 * w + lc;

    // ---- stage obs tile (fp32 -> bf16, swizzled) + opts ----
    {
        const float* op = obs + (size_t)tile * 64 * OBS_DIM;
#pragma unroll
        for (int i = 0; i < 16; ++i) {
            int flat = tid * 4 + i * 1024;
            float4 v = *reinterpret_cast<const float4*>(op + flat);
            int row = flat >> 8, col = flat & 255;
            u16x4 u;
            u.x = bf(v.x); u.y = bf(v.y); u.z = bf(v.z); u.w = bf(v.w);
            *reinterpret_cast<u16x4*>(lA + row * 512 + SWZ(row, col * 2)) = u;
        }
        if (tid < 64) lOpt[tid] = opt[tile * 64 + tid];
    }
    __syncthreads();

    // ---- trunk layer 1 ----
    {
        f32x4 acc1[4] = {{0,0,0,0},{0,0,0,0},{0,0,0,0},{0,0,0,0}};
#pragma unroll
        for (int ks = 0; ks < 8; ++ks) {
            short8 a = *reinterpret_cast<const short8*>(lA + arow * 512 + SWZ(arow, ks * 64 + lg * 16));
#pragma unroll
            for (int nn = 0; nn < 4; ++nn) {
                short8 b = *reinterpret_cast<const short8*>(fW1b + (nn * 16 + lc) * 256 + ks * 32 + lg * 8);
                acc1[nn] = MFMA(a, b, acc1[nn]);
            }
        }
#pragma unroll
        for (int nn = 0; nn < 4; ++nn) {
            int col = nn * 16 + lc;
            float bias = fb1[col];
#pragma unroll
            for (int r = 0; r < 4; ++r) {
                int row = 16 * w + 4 * lg + r;
                *(u16*)(lH + row * 128 + SWZ(row, col * 2)) = bf(fmaxf(acc1[nn][r] + bias, 0.f));
            }
        }
    }
    __syncthreads();

    // ---- trunk layer 2 (writes lS, aliasing dead lA) ----
    {
        f32x4 acc2[8];
#pragma unroll
        for (int nn = 0; nn < 8; ++nn) acc2[nn] = (f32x4){0,0,0,0};
#pragma unroll
        for (int ks = 0; ks < 2; ++ks) {
            short8 a = *reinterpret_cast<const short8*>(lH + arow * 128 + SWZ(arow, ks * 64 + lg * 16));
#pragma unroll
            for (int nn = 0; nn < 8; ++nn) {
                short8 b = *reinterpret_cast<const short8*>(fW2b + (nn * 16 + lc) * 64 + ks * 32 + lg * 8);
                acc2[nn] = MFMA(a, b, acc2[nn]);
            }
        }
#pragma unroll
        for (int nn = 0; nn < 8; ++nn) {
            int col = nn * 16 + lc;
            float bias = fb2[col];
#pragma unroll
            for (int r = 0; r < 4; ++r) {
                int row = 16 * w + 4 * lg + r;
                *(u16*)(lS + row * 256 + SWZ(row, col * 2)) = bf(fmaxf(acc2[nn][r] + bias, 0.f));
            }
        }
    }
    __syncthreads();

    // per-band row options (registers, reused by both expert phases)
    int ro[4];
#pragma unroll
    for (int r = 0; r < 4; ++r) ro[r] = lOpt[16 * w + 4 * lg + r];

    // ---- heads: optval + termprob ----
    {
        f32x4 accP = {0,0,0,0}, accT = {0,0,0,0};
#pragma unroll
        for (int ks = 0; ks < 4; ++ks) {
            short8 a = *reinterpret_cast<const short8*>(lS + arow * 256 + SWZ(arow, ks * 64 + lg * 16));
            short8 bp = *reinterpret_cast<const short8*>(pWb + lc * 128 + ks * 32 + lg * 8);
            short8 bt = *reinterpret_cast<const short8*>(tWb + lc * 128 + ks * 32 + lg * 8);
            accP = MFMA(a, bp, accP);
            accT = MFMA(a, bt, accT);
        }
#pragma unroll
        for (int r = 0; r < 4; ++r) {
            int grow = tile * 64 + 16 * w + 4 * lg + r;
            int o = ro[r];
            float pv = __shfl(accP[r], (l & 48) | o, 64);
            float tv = __shfl(accT[r], (l & 48) | o, 64);
            if (lc == 0) {
                out[BATCH + grow] = pv + pb[o];
                out[2 * BATCH + grow] = 1.f / (1.f + expf(-(tv + tb[o])));
            }
        }
    }

    // ---- expert layer 1: all 8 options, predicated select by opt ----
    {
        short8 a4[4];
#pragma unroll
        for (int ks = 0; ks < 4; ++ks)
            a4[ks] = *reinterpret_cast<const short8*>(lS + arow * 256 + SWZ(arow, ks * 64 + lg * 16));
#pragma unroll
        for (int o = 0; o < N_OPT; ++o) {
            const u16* W1 = oW1b + o * HID * FEAT;
            f32x4 acc[4] = {{0,0,0,0},{0,0,0,0},{0,0,0,0},{0,0,0,0}};
#pragma unroll
            for (int ks = 0; ks < 4; ++ks) {
#pragma unroll
                for (int nn = 0; nn < 4; ++nn) {
                    short8 b = *reinterpret_cast<const short8*>(W1 + (nn * 16 + lc) * 128 + ks * 32 + lg * 8);
                    acc[nn] = MFMA(a4[ks], b, acc[nn]);
                }
            }
#pragma unroll
            for (int nn = 0; nn < 4; ++nn) {
                int col = nn * 16 + lc;
                float bias = ob1[o * HID + col];
#pragma unroll
                for (int r = 0; r < 4; ++r) {
                    if (ro[r] == o) {
                        int row = 16 * w + 4 * lg + r;
                        *(u16*)(lE + row * 128 + SWZ(row, col * 2)) = bf(fmaxf(acc[nn][r] + bias, 0.f));
                    }
                }
            }
        }
    }
    __syncthreads();

    // ---- expert layer 2: all 8 options, select into logits ----
    {
        short8 a2[2];
#pragma unroll
        for (int ks = 0; ks < 2; ++ks)
            a2[ks] = *reinterpret_cast<const short8*>(lE + arow * 128 + SWZ(arow, ks * 64 + lg * 16));
#pragma unroll
        for (int o = 0; o < N_OPT; ++o) {
            const u16* W2 = oW2b + o * 32 * HID;
            f32x4 acc2[2] = {{0,0,0,0},{0,0,0,0}};
#pragma unroll
            for (int ks = 0; ks < 2; ++ks) {
#pragma unroll
                for (int nn = 0; nn < 2; ++nn) {
                    short8 b = *reinterpret_cast<const short8*>(W2 + (nn * 16 + lc) * 64 + ks * 32 + lg * 8);
                    acc2[nn] = MFMA(a2[ks], b, acc2[nn]);
                }
            }
#pragma unroll
            for (int nn = 0; nn < 2; ++nn) {
                int col = nn * 16 + lc;
                if (col < ACT_N) {
                    float bias = ob2[o * ACT_N + col];
#pragma unroll
                    for (int r = 0; r < 4; ++r) {
                        if (ro[r] == o) {
                            int row = 16 * w + 4 * lg + r;
                            lL[row * 19 + col] = acc2[nn][r] + bias;
                        }
                    }
                }
            }
        }
    }
    __syncthreads();

    // ---- log-softmax + gather(act): 4 lanes per row ----
    {
        int row = tid >> 2, q = tid & 3;
        int grow = tile * 64 + row;
        const float* lr = lL + row * 19;
        float mx = -1e30f;
        for (int a = q; a < ACT_N; a += 4) mx = fmaxf(mx, lr[a]);
        mx = fmaxf(mx, __shfl_xor(mx, 1, 64));
        mx = fmaxf(mx, __shfl_xor(mx, 2, 64));
        float s = 0.f;
        for (int a = q; a < ACT_N; a += 4) s += expf(lr[a] - mx);
        s += __shfl_xor(s, 1, 64);
        s += __shfl_xor(s, 2, 64);
        if (q == 0) {
            int aa = act[grow];
            out[grow] = (lr[aa] - mx) - logf(s);
        }
    }
}

// ---------------------------------------------------------------------------
extern "C" void kernel_launch(void* const* d_in, const int* in_sizes, int n_in,
                              void* d_out, int out_size, void* d_ws, size_t ws_size,
                              hipStream_t stream) {
    const float* obs = (const float*)d_in[0];
    const int*   act = (const int*)d_in[1];
    const int*   opt = (const int*)d_in[2];
    const float* fW1 = (const float*)d_in[3];
    const float* fb1 = (const float*)d_in[4];
    const float* fW2 = (const float*)d_in[5];
    const float* fb2 = (const float*)d_in[6];
    const float* pW  = (const float*)d_in[7];
    const float* pb  = (const float*)d_in[8];
    const float* tW  = (const float*)d_in[9];
    const float* tb  = (const float*)d_in[10];
    const float* oW1 = (const float*)d_in[11];
    const float* ob1 = (const float*)d_in[12];
    const float* oW2 = (const float*)d_in[13];
    const float* ob2 = (const float*)d_in[14];
    float* out = (float*)d_out;

    char* ws = (char*)d_ws;
    u16* fW1b = (u16*)(ws + WS_FW1);
    u16* fW2b = (u16*)(ws + WS_FW2);
    u16* pWb  = (u16*)(ws + WS_PW);
    u16* tWb  = (u16*)(ws + WS_TW);
    u16* oW1b = (u16*)(ws + WS_OW1);
    u16* oW2b = (u16*)(ws + WS_OW2);

    k_prep<<<64, 256, 0, stream>>>(fW1, fW2, pW, tW, oW1, oW2,
                                   fW1b, fW2b, pWb, tWb, oW1b, oW2b);
    k_fused<<<BATCH / 64, 256, 0, stream>>>(obs, opt, act,
                                            fW1b, fb1, fW2b, fb2,
                                            pWb, pb, tWb, tb,
                                            oW1b, ob1, oW2b, ob2, out);
}

// Round 6
// 131.869 us; speedup vs baseline: 1.1593x; 1.1593x over previous
//
#include <hip/hip_runtime.h>
#include <hip/hip_bf16.h>
#include <math.h>

#define OBS_DIM 256
#define FEAT 128
#define HID 64
#define N_OPT 8
#define ACT_N 18
#define BATCH 32768

typedef unsigned short u16;
typedef unsigned int u32;
typedef __attribute__((ext_vector_type(8))) short short8;
typedef __attribute__((ext_vector_type(4))) float f32x4;
typedef __attribute__((ext_vector_type(4))) u16 u16x4;

#define MFMA(a, b, c) __builtin_amdgcn_mfma_f32_16x16x32_bf16((a), (b), (c), 0, 0, 0)

// XOR swizzle (T2): spread same-column ds_read_b128 frags across 8 16B slots.
#define SWZ(row, off) ((off) ^ (((row) & 7) << 4))

// ---- ws layout (bytes): bf16 weights only ----
#define WS_FW1 0                        // [64][256]
#define WS_FW2 (WS_FW1 + 64*256*2)      // [128][64]
#define WS_PW  (WS_FW2 + 128*64*2)      // [16][128] zero-padded rows 8..15
#define WS_TW  (WS_PW  + 16*128*2)      // [16][128] zero-padded
#define WS_OW1 (WS_TW  + 16*128*2)      // [8][64][128]
#define WS_OW2 (WS_OW1 + 8*64*128*2)    // [8][32][64] zero-padded rows 18..31

// ---- LDS arena (bytes). Temporal aliasing:
//  lA   [0,32768)      obs tile      (stage .. trunk L1)
//  lH   [32768,40960)  trunk hidden  (L1 .. L2)          — inside wbuf1, dead before first write
//  lS   [40960,57344)  state         (L2 .. a4 loads)    — overlaps lE/lL, dead before their writes
//  wbuf0[0,20480) wbuf1[20480,40960) expert W dbuf       (option loop)
//  lE   [40960,49152)  expert hidden (option loop)
//  lL   [49152,54016)  logits f32    (option loop .. softmax)
#define L_A   0
#define L_H   32768
#define L_S   40960
#define L_WB0 0
#define L_WB1 20480
#define L_E   40960
#define L_LL  49152
#define ARENA 57344

__device__ __forceinline__ u16 bf(float x) {  // RNE f32->bf16
    u32 u = __float_as_uint(x);
    return (u16)((u + 0x7fffu + ((u >> 16) & 1u)) >> 16);
}

// ---------------------------------------------------------------------------
// K0: weight conversion fp32 -> bf16 (+ zero padding). Re-run every launch.
// ---------------------------------------------------------------------------
__global__ __launch_bounds__(256) void k_prep(
    const float* __restrict__ fW1, const float* __restrict__ fW2,
    const float* __restrict__ pW,  const float* __restrict__ tW,
    const float* __restrict__ oW1, const float* __restrict__ oW2,
    u16* __restrict__ fW1b, u16* __restrict__ fW2b,
    u16* __restrict__ pWb,  u16* __restrict__ tWb,
    u16* __restrict__ oW1b, u16* __restrict__ oW2b)
{
    int gid = blockIdx.x * 256 + threadIdx.x;
    int stride = gridDim.x * 256;
    for (int i = gid; i < 64 * 256; i += stride) fW1b[i] = bf(fW1[i]);
    for (int i = gid; i < 128 * 64; i += stride) fW2b[i] = bf(fW2[i]);
    for (int i = gid; i < 16 * 128; i += stride) {
        int r = i >> 7;
        pWb[i] = (r < 8) ? bf(pW[i]) : (u16)0;
        tWb[i] = (r < 8) ? bf(tW[i]) : (u16)0;
    }
    for (int i = gid; i < 8 * 64 * 128; i += stride) oW1b[i] = bf(oW1[i]);
    for (int i = gid; i < 8 * 32 * 64; i += stride) {
        int o = i >> 11, a = (i >> 6) & 31, e = i & 63;
        oW2b[i] = (a < ACT_N) ? bf(oW2[(o * ACT_N + a) * 64 + e]) : (u16)0;
    }
}

// ---------------------------------------------------------------------------
// K1: fully fused, expert weights LDS-staged + double-buffered.
// ---------------------------------------------------------------------------
__global__ __launch_bounds__(256, 2) void k_fused(
    const float* __restrict__ obs, const int* __restrict__ opt,
    const int* __restrict__ act,
    const u16* __restrict__ fW1b, const float* __restrict__ fb1,
    const u16* __restrict__ fW2b, const float* __restrict__ fb2,
    const u16* __restrict__ pWb,  const float* __restrict__ pb,
    const u16* __restrict__ tWb,  const float* __restrict__ tb,
    const u16* __restrict__ oW1b, const float* __restrict__ ob1,
    const u16* __restrict__ oW2b, const float* __restrict__ ob2,
    float* __restrict__ out)
{
    __shared__ char lmem[ARENA];
    __shared__ int lOpt[64];
    float* lL = (float*)(lmem + L_LL);

    const int tid = threadIdx.x;
    const int tile = blockIdx.x;
    const int w = tid >> 6, l = tid & 63, lg = l >> 4, lc = l & 15;
    const int arow = 16 * w + lc;

    // ---- stage obs tile (fp32 -> bf16, swizzled) + opts ----
    {
        const float* op = obs + (size_t)tile * 64 * OBS_DIM;
        float4 ov[16];
#pragma unroll
        for (int i = 0; i < 16; ++i)
            ov[i] = *reinterpret_cast<const float4*>(op + tid * 4 + i * 1024);
        if (tid < 64) lOpt[tid] = opt[tile * 64 + tid];
#pragma unroll
        for (int i = 0; i < 16; ++i) {
            int flat = tid * 4 + i * 1024;
            int row = flat >> 8, col = flat & 255;
            u16x4 u;
            u.x = bf(ov[i].x); u.y = bf(ov[i].y); u.z = bf(ov[i].z); u.w = bf(ov[i].w);
            *reinterpret_cast<u16x4*>(lmem + L_A + row * 512 + SWZ(row, col * 2)) = u;
        }
    }
    __syncthreads();

    // ---- trunk layer 1 (A from LDS, B from global/L2) ----
    {
        f32x4 acc1[4] = {{0,0,0,0},{0,0,0,0},{0,0,0,0},{0,0,0,0}};
#pragma unroll
        for (int ks = 0; ks < 8; ++ks) {
            short8 a = *reinterpret_cast<const short8*>(lmem + L_A + arow * 512 + SWZ(arow, ks * 64 + lg * 16));
#pragma unroll
            for (int nn = 0; nn < 4; ++nn) {
                short8 b = *reinterpret_cast<const short8*>(fW1b + (nn * 16 + lc) * 256 + ks * 32 + lg * 8);
                acc1[nn] = MFMA(a, b, acc1[nn]);
            }
        }
#pragma unroll
        for (int nn = 0; nn < 4; ++nn) {
            int col = nn * 16 + lc;
            float bias = fb1[col];
#pragma unroll
            for (int r = 0; r < 4; ++r) {
                int row = 16 * w + 4 * lg + r;
                *(u16*)(lmem + L_H + row * 128 + SWZ(row, col * 2)) = bf(fmaxf(acc1[nn][r] + bias, 0.f));
            }
        }
    }
    __syncthreads();

    // head B-frags: issue early, consumed after trunk L2
    short8 bpr[4], btr[4];
#pragma unroll
    for (int ks = 0; ks < 4; ++ks) {
        bpr[ks] = *reinterpret_cast<const short8*>(pWb + lc * 128 + ks * 32 + lg * 8);
        btr[ks] = *reinterpret_cast<const short8*>(tWb + lc * 128 + ks * 32 + lg * 8);
    }
    // expert option-0 weights: issue early, ds-written after heads
    short8 er[5];
    {
        const u16* w1g = oW1b;
        const u16* w2g = oW2b;
#pragma unroll
        for (int j = 0; j < 4; ++j) er[j] = *reinterpret_cast<const short8*>(w1g + (j * 256 + tid) * 8);
        er[4] = *reinterpret_cast<const short8*>(w2g + tid * 8);
    }

    // ---- trunk layer 2 ----
    {
        f32x4 acc2[8];
#pragma unroll
        for (int nn = 0; nn < 8; ++nn) acc2[nn] = (f32x4){0,0,0,0};
#pragma unroll
        for (int ks = 0; ks < 2; ++ks) {
            short8 a = *reinterpret_cast<const short8*>(lmem + L_H + arow * 128 + SWZ(arow, ks * 64 + lg * 16));
#pragma unroll
            for (int nn = 0; nn < 8; ++nn) {
                short8 b = *reinterpret_cast<const short8*>(fW2b + (nn * 16 + lc) * 64 + ks * 32 + lg * 8);
                acc2[nn] = MFMA(a, b, acc2[nn]);
            }
        }
#pragma unroll
        for (int nn = 0; nn < 8; ++nn) {
            int col = nn * 16 + lc;
            float bias = fb2[col];
#pragma unroll
            for (int r = 0; r < 4; ++r) {
                int row = 16 * w + 4 * lg + r;
                *(u16*)(lmem + L_S + row * 256 + SWZ(row, col * 2)) = bf(fmaxf(acc2[nn][r] + bias, 0.f));
            }
        }
    }
    __syncthreads();

    // per-band row options
    int ro[4];
#pragma unroll
    for (int r = 0; r < 4; ++r) ro[r] = lOpt[16 * w + 4 * lg + r];

    // A-frags of state: loaded ONCE, reused by heads + all 8 expert options
    short8 a4[4];
#pragma unroll
    for (int ks = 0; ks < 4; ++ks)
        a4[ks] = *reinterpret_cast<const short8*>(lmem + L_S + arow * 256 + SWZ(arow, ks * 64 + lg * 16));

    // ---- heads ----
    {
        f32x4 accP = {0,0,0,0}, accT = {0,0,0,0};
#pragma unroll
        for (int ks = 0; ks < 4; ++ks) {
            accP = MFMA(a4[ks], bpr[ks], accP);
            accT = MFMA(a4[ks], btr[ks], accT);
        }
#pragma unroll
        for (int r = 0; r < 4; ++r) {
            int grow = tile * 64 + 16 * w + 4 * lg + r;
            int o = ro[r];
            float pv = __shfl(accP[r], (l & 48) | o, 64);
            float tv = __shfl(accT[r], (l & 48) | o, 64);
            if (lc == 0) {
                out[BATCH + grow] = pv + pb[o];
                out[2 * BATCH + grow] = 1.f / (1.f + expf(-(tv + tb[o])));
            }
        }
    }
    __syncthreads();   // all waves have a4; lS region may now be overwritten (wbuf0/lE/lL alias)

    // ---- prologue: W0 -> wbuf0; issue W1 loads ----
    {
        char* nb = lmem + L_WB0;
#pragma unroll
        for (int j = 0; j < 4; ++j) {
            int flat = (j * 256 + tid) * 16;
            int r = flat >> 8, c2 = flat & 255;
            *reinterpret_cast<short8*>(nb + r * 256 + SWZ(r, c2)) = er[j];
        }
        int flat2 = tid * 16;
        int r2 = flat2 >> 7, c22 = flat2 & 127;
        *reinterpret_cast<short8*>(nb + 16384 + r2 * 128 + SWZ(r2, c22)) = er[4];

        const u16* w1g = oW1b + 8192;
        const u16* w2g = oW2b + 2048;
#pragma unroll
        for (int j = 0; j < 4; ++j) er[j] = *reinterpret_cast<const short8*>(w1g + (j * 256 + tid) * 8);
        er[4] = *reinterpret_cast<const short8*>(w2g + tid * 8);
    }
    __syncthreads();

    // ---- expert option loop: compute o from wbuf[o&1]; stage o+1; load o+2 ----
    for (int o = 0; o < N_OPT; ++o) {
        const char* wb = lmem + ((o & 1) ? L_WB1 : L_WB0);

        // expert L1 (16 MFMA)
        f32x4 acc[4] = {{0,0,0,0},{0,0,0,0},{0,0,0,0},{0,0,0,0}};
#pragma unroll
        for (int ks = 0; ks < 4; ++ks) {
#pragma unroll
            for (int nn = 0; nn < 4; ++nn) {
                short8 b = *reinterpret_cast<const short8*>(wb + (nn * 16 + lc) * 256 + SWZ(nn * 16 + lc, ks * 64 + lg * 16));
                acc[nn] = MFMA(a4[ks], b, acc[nn]);
            }
        }
#pragma unroll
        for (int nn = 0; nn < 4; ++nn) {
            int col = nn * 16 + lc;
            float bias = ob1[o * HID + col];
#pragma unroll
            for (int r = 0; r < 4; ++r) {
                if (ro[r] == o) {
                    int row = 16 * w + 4 * lg + r;
                    *(u16*)(lmem + L_E + row * 128 + SWZ(row, col * 2)) = bf(fmaxf(acc[nn][r] + bias, 0.f));
                }
            }
        }
        __syncthreads();

        // expert L2 (4 MFMA)
        short8 a2[2];
#pragma unroll
        for (int ks = 0; ks < 2; ++ks)
            a2[ks] = *reinterpret_cast<const short8*>(lmem + L_E + arow * 128 + SWZ(arow, ks * 64 + lg * 16));
        f32x4 accl[2] = {{0,0,0,0},{0,0,0,0}};
#pragma unroll
        for (int ks = 0; ks < 2; ++ks) {
#pragma unroll
            for (int nn = 0; nn < 2; ++nn) {
                short8 b = *reinterpret_cast<const short8*>(wb + 16384 + (nn * 16 + lc) * 128 + SWZ(nn * 16 + lc, ks * 64 + lg * 16));
                accl[nn] = MFMA(a2[ks], b, accl[nn]);
            }
        }
#pragma unroll
        for (int nn = 0; nn < 2; ++nn) {
            int col = nn * 16 + lc;
            if (col < ACT_N) {
                float bias = ob2[o * ACT_N + col];
#pragma unroll
                for (int r = 0; r < 4; ++r) {
                    if (ro[r] == o) {
                        int row = 16 * w + 4 * lg + r;
                        lL[row * 19 + col] = accl[nn][r] + bias;
                    }
                }
            }
        }

        // stage W(o+1) into the buffer freed at the o-1 barrier; issue W(o+2)
        if (o < 7) {
            char* nb = lmem + ((o & 1) ? L_WB0 : L_WB1);
#pragma unroll
            for (int j = 0; j < 4; ++j) {
                int flat = (j * 256 + tid) * 16;
                int r = flat >> 8, c2 = flat & 255;
                *reinterpret_cast<short8*>(nb + r * 256 + SWZ(r, c2)) = er[j];
            }
            int flat2 = tid * 16;
            int r2 = flat2 >> 7, c22 = flat2 & 127;
            *reinterpret_cast<short8*>(nb + 16384 + r2 * 128 + SWZ(r2, c22)) = er[4];
            if (o < 6) {
                const u16* w1g = oW1b + (o + 2) * 8192;
                const u16* w2g = oW2b + (o + 2) * 2048;
#pragma unroll
                for (int j = 0; j < 4; ++j) er[j] = *reinterpret_cast<const short8*>(w1g + (j * 256 + tid) * 8);
                er[4] = *reinterpret_cast<const short8*>(w2g + tid * 8);
            }
        }
        __syncthreads();
    }

    // ---- log-softmax + gather(act): 4 lanes per row ----
    {
        int row = tid >> 2, q = tid & 3;
        int grow = tile * 64 + row;
        const float* lr = lL + row * 19;
        float mx = -1e30f;
        for (int a = q; a < ACT_N; a += 4) mx = fmaxf(mx, lr[a]);
        mx = fmaxf(mx, __shfl_xor(mx, 1, 64));
        mx = fmaxf(mx, __shfl_xor(mx, 2, 64));
        float s = 0.f;
        for (int a = q; a < ACT_N; a += 4) s += expf(lr[a] - mx);
        s += __shfl_xor(s, 1, 64);
        s += __shfl_xor(s, 2, 64);
        if (q == 0) {
            int aa = act[grow];
            out[grow] = (lr[aa] - mx) - logf(s);
        }
    }
}

// ---------------------------------------------------------------------------
extern "C" void kernel_launch(void* const* d_in, const int* in_sizes, int n_in,
                              void* d_out, int out_size, void* d_ws, size_t ws_size,
                              hipStream_t stream) {
    const float* obs = (const float*)d_in[0];
    const int*   act = (const int*)d_in[1];
    const int*   opt = (const int*)d_in[2];
    const float* fW1 = (const float*)d_in[3];
    const float* fb1 = (const float*)d_in[4];
    const float* fW2 = (const float*)d_in[5];
    const float* fb2 = (const float*)d_in[6];
    const float* pW  = (const float*)d_in[7];
    const float* pb  = (const float*)d_in[8];
    const float* tW  = (const float*)d_in[9];
    const float* tb  = (const float*)d_in[10];
    const float* oW1 = (const float*)d_in[11];
    const float* ob1 = (const float*)d_in[12];
    const float* oW2 = (const float*)d_in[13];
    const float* ob2 = (const float*)d_in[14];
    float* out = (float*)d_out;

    char* ws = (char*)d_ws;
    u16* fW1b = (u16*)(ws + WS_FW1);
    u16* fW2b = (u16*)(ws + WS_FW2);
    u16* pWb  = (u16*)(ws + WS_PW);
    u16* tWb  = (u16*)(ws + WS_TW);
    u16* oW1b = (u16*)(ws + WS_OW1);
    u16* oW2b = (u16*)(ws + WS_OW2);

    k_prep<<<64, 256, 0, stream>>>(fW1, fW2, pW, tW, oW1, oW2,
                                   fW1b, fW2b, pWb, tWb, oW1b, oW2b);
    k_fused<<<BATCH / 64, 256, 0, stream>>>(obs, opt, act,
                                            fW1b, fb1, fW2b, fb2,
                                            pWb, pb, tWb, tb,
                                            oW1b, ob1, oW2b, ob2, out);
}

// Round 7
// 119.466 us; speedup vs baseline: 1.2797x; 1.1038x over previous
//
#include <hip/hip_runtime.h>
#include <hip/hip_bf16.h>
#include <math.h>

#define OBS_DIM 256
#define FEAT 128
#define HID 64
#define N_OPT 8
#define ACT_N 18
#define BATCH 32768

typedef unsigned short u16;
typedef unsigned int u32;
typedef __attribute__((ext_vector_type(8))) short short8;
typedef __attribute__((ext_vector_type(4))) float f32x4;

#define MFMA(a, b, c) __builtin_amdgcn_mfma_f32_16x16x32_bf16((a), (b), (c), 0, 0, 0)

union frag_u { u32 u[4]; short8 s; };

// ---- ws layout (u16 units), ALL weights pre-permuted frag-major by k_prep:
//   trkw: 56 frags x 512 u16 = 56 KB   (fW1 f0-31, fW2 f32-47, pW f48-51, tW f52-55)
//   expw: 8 options x 20 frags x 512   (per option: W1 f0-15, W2 f16-19) = 160 KB
// frag content: lane l=(lg=l>>4, lc=l&15), 8 bf16 = W[row=nn*16+lc][ks*32+lg*8 .. +8)
#define TRK_U16 28672
#define EXP_U16 81920

// ---- LDS map (bytes), temporal aliasing:
//   [0,57344)  staged trunk weights (56 frags)      -> dead in stages:
//       wbuf0 [0,20480)    expert dbuf A   (gll after post-L1 barrier)
//       lS    [20480,36864) state A-frag-major (written post-L2 barrier)
//       wbuf1 [20480,40960) expert dbuf B   (gll after post-heads barrier)
//       lL    [49152,54016) logits f32      (written in option loop)
//   [57344,65536) lH trunk-hidden A-frag-major -> lE expert-hidden (option loop)
#define L_WB0 0
#define L_S   20480
#define L_WB1 20480
#define L_PW  49152
#define L_TW  53248
#define L_LL  49152
#define L_LH  57344
#define L_E   57344

__device__ __forceinline__ u16 bf(float x) {  // RNE f32->bf16
    u32 u = __float_as_uint(x);
    return (u16)((u + 0x7fffu + ((u >> 16) & 1u)) >> 16);
}
__device__ __forceinline__ u32 cvtpk(float lo, float hi) {  // 2xf32 -> packed 2xbf16 (RNE)
    u32 r;
    asm("v_cvt_pk_bf16_f32 %0, %1, %2" : "=v"(r) : "v"(lo), "v"(hi));
    return r;
}

// ---------------------------------------------------------------------------
// K0: build frag-major bf16 weight images (dst-linear writes, decoded source).
// ---------------------------------------------------------------------------
__global__ __launch_bounds__(256) void k_prep(
    const float* __restrict__ fW1, const float* __restrict__ fW2,
    const float* __restrict__ pW,  const float* __restrict__ tW,
    const float* __restrict__ oW1, const float* __restrict__ oW2,
    u16* __restrict__ dst)
{
    int gid = blockIdx.x * 256 + threadIdx.x;
    int stride = gridDim.x * 256;
    for (int i = gid; i < TRK_U16 + EXP_U16; i += stride) {
        float v;
        if (i < TRK_U16) {
            int f = i >> 9, l = (i >> 3) & 63, j = i & 7;
            int lc = l & 15, lg = l >> 4;
            if (f < 32) {
                int ks = f >> 2, nn = f & 3;
                v = fW1[(nn * 16 + lc) * 256 + ks * 32 + lg * 8 + j];
            } else if (f < 48) {
                int f2 = f - 32, ks = f2 >> 3, nn = f2 & 7;
                v = fW2[(nn * 16 + lc) * 64 + ks * 32 + lg * 8 + j];
            } else if (f < 52) {
                int ks = f - 48;
                v = (lc < N_OPT) ? pW[lc * 128 + ks * 32 + lg * 8 + j] : 0.f;
            } else {
                int ks = f - 52;
                v = (lc < N_OPT) ? tW[lc * 128 + ks * 32 + lg * 8 + j] : 0.f;
            }
        } else {
            int t = i - TRK_U16;
            int o = t / 10240, t2 = t - o * 10240;
            int f = t2 >> 9, l = (t2 >> 3) & 63, j = t2 & 7;
            int lc = l & 15, lg = l >> 4;
            if (f < 16) {
                int ks = f >> 2, nn = f & 3;
                v = oW1[o * 8192 + (nn * 16 + lc) * 128 + ks * 32 + lg * 8 + j];
            } else {
                int f2 = f - 16, ks = f2 >> 1, nn = f2 & 1;
                int row = nn * 16 + lc;
                v = (row < ACT_N) ? oW2[o * (ACT_N * 64) + row * 64 + ks * 32 + lg * 8 + j] : 0.f;
            }
        }
        dst[i] = bf(v);
    }
}

// ---------------------------------------------------------------------------
// K1: fully fused; all B-operands via global_load_lds-staged frag-major LDS.
// 64 rows/block, 4 waves; obs A-frags loaded straight into registers.
// ---------------------------------------------------------------------------
__global__ __launch_bounds__(256, 2) void k_fused(
    const float* __restrict__ obs, const int* __restrict__ opt,
    const int* __restrict__ act,
    const u16* __restrict__ trkw, const u16* __restrict__ expw,
    const float* __restrict__ fb1, const float* __restrict__ fb2,
    const float* __restrict__ pb,  const float* __restrict__ tb,
    const float* __restrict__ ob1, const float* __restrict__ ob2,
    float* __restrict__ out)
{
    __shared__ char lmem[65536];
    const int tid = threadIdx.x;
    const int tile = blockIdx.x;
    const int w = tid >> 6, l = tid & 63, lg = l >> 4, lc = l & 15;
    const int l16 = l * 16;

    // ---- early global loads (obs FIRST: vmcnt retires in order) ----
    const float* orow = obs + (size_t)(tile * 64 + 16 * w + lc) * OBS_DIM + lg * 8;
    float4 of[16];
#pragma unroll
    for (int ks = 0; ks < 8; ++ks) {
        of[2 * ks]     = *reinterpret_cast<const float4*>(orow + ks * 32);
        of[2 * ks + 1] = *reinterpret_cast<const float4*>(orow + ks * 32 + 4);
    }
    int ro[4];
#pragma unroll
    for (int r = 0; r < 4; ++r) ro[r] = opt[tile * 64 + 16 * w + 4 * lg + r];
    int myact = act[tile * 64 + (tid >> 2)];
    float fb1v[4], fb2v[8];
#pragma unroll
    for (int nn = 0; nn < 4; ++nn) fb1v[nn] = fb1[nn * 16 + lc];
#pragma unroll
    for (int nn = 0; nn < 8; ++nn) fb2v[nn] = fb2[nn * 16 + lc];

    // ---- stage all trunk weights (56 frags, 14 per wave) ----
#pragma unroll
    for (int i = 0; i < 14; ++i) {
        int f = w * 14 + i;
        __builtin_amdgcn_global_load_lds((const void*)(trkw + f * 512 + l * 8),
                                         (void*)(lmem + f * 1024), 16, 0, 0);
    }

    // ---- convert obs -> 8 A-frags in registers ----
    frag_u a1[8];
#pragma unroll
    for (int ks = 0; ks < 8; ++ks) {
        a1[ks].u[0] = cvtpk(of[2 * ks].x,     of[2 * ks].y);
        a1[ks].u[1] = cvtpk(of[2 * ks].z,     of[2 * ks].w);
        a1[ks].u[2] = cvtpk(of[2 * ks + 1].x, of[2 * ks + 1].y);
        a1[ks].u[3] = cvtpk(of[2 * ks + 1].z, of[2 * ks + 1].w);
    }
    float pbr[4], tbr[4];
#pragma unroll
    for (int r = 0; r < 4; ++r) { pbr[r] = pb[ro[r]]; tbr[r] = tb[ro[r]]; }

    __syncthreads();   // trunk weights staged (barrier drains vmcnt)

    // ---- trunk L1: 32 ds_read_b128 (lane-contiguous) + 32 MFMA ----
    f32x4 acc1[4] = {{0,0,0,0},{0,0,0,0},{0,0,0,0},{0,0,0,0}};
#pragma unroll
    for (int ks = 0; ks < 8; ++ks) {
#pragma unroll
        for (int nn = 0; nn < 4; ++nn) {
            short8 b = *reinterpret_cast<const short8*>(lmem + (ks * 4 + nn) * 1024 + l16);
            acc1[nn] = MFMA(a1[ks].s, b, acc1[nn]);
        }
    }
    // epilogue -> lH (A-frag-major, own-wave region: no barrier vs own reads)
#pragma unroll
    for (int nn = 0; nn < 4; ++nn) {
#pragma unroll
        for (int r = 0; r < 4; ++r) {
            u16 hv = bf(fmaxf(acc1[nn][r] + fb1v[nn], 0.f));
            int ad = L_LH + w * 2048 + (nn >> 1) * 1024
                   + (((((nn & 1) * 2 + (lc >> 3)) * 16) + 4 * lg + r) << 4) + ((lc & 7) << 1);
            *(u16*)(lmem + ad) = hv;
        }
    }
    __syncthreads();   // all waves done with fW1 region -> wbuf0 may be overwritten

    // ---- stage expert option-0 -> wbuf0 (drained at post-heads barrier) ----
#pragma unroll
    for (int i = 0; i < 5; ++i) {
        int f = w * 5 + i;
        __builtin_amdgcn_global_load_lds((const void*)(expw + f * 512 + l * 8),
                                         (void*)(lmem + L_WB0 + f * 1024), 16, 0, 0);
    }

    // ---- trunk L2 ----
    f32x4 acc2[8];
#pragma unroll
    for (int nn = 0; nn < 8; ++nn) acc2[nn] = (f32x4){0,0,0,0};
#pragma unroll
    for (int ks = 0; ks < 2; ++ks) {
        short8 a = *reinterpret_cast<const short8*>(lmem + L_LH + w * 2048 + ks * 1024 + l16);
#pragma unroll
        for (int nn = 0; nn < 8; ++nn) {
            short8 b = *reinterpret_cast<const short8*>(lmem + (32 + ks * 8 + nn) * 1024 + l16);
            acc2[nn] = MFMA(a, b, acc2[nn]);
        }
    }
    __syncthreads();   // fW2 + lH reads done everywhere -> lS region free

    // ---- state -> lS (A-frag-major) ----
#pragma unroll
    for (int nn = 0; nn < 8; ++nn) {
#pragma unroll
        for (int r = 0; r < 4; ++r) {
            u16 sv = bf(fmaxf(acc2[nn][r] + fb2v[nn], 0.f));
            int ad = L_S + w * 4096 + (nn >> 1) * 1024
                   + (((((nn & 1) * 2 + (lc >> 3)) * 16) + 4 * lg + r) << 4) + ((lc & 7) << 1);
            *(u16*)(lmem + ad) = sv;
        }
    }
    // a4: own-wave region, LDS pipe is in-order per wave -> no barrier
    short8 a4[4];
#pragma unroll
    for (int ks = 0; ks < 4; ++ks)
        a4[ks] = *reinterpret_cast<const short8*>(lmem + L_S + w * 4096 + ks * 1024 + l16);

    // ---- heads (staged pW/tW frags) ----
    f32x4 accP = {0,0,0,0}, accT = {0,0,0,0};
#pragma unroll
    for (int ks = 0; ks < 4; ++ks) {
        short8 bp = *reinterpret_cast<const short8*>(lmem + L_PW + ks * 1024 + l16);
        short8 bt = *reinterpret_cast<const short8*>(lmem + L_TW + ks * 1024 + l16);
        accP = MFMA(a4[ks], bp, accP);
        accT = MFMA(a4[ks], bt, accT);
    }
#pragma unroll
    for (int r = 0; r < 4; ++r) {
        int grow = tile * 64 + 16 * w + 4 * lg + r;
        float pv = __shfl(accP[r], (l & 48) | ro[r], 64);
        float tv = __shfl(accT[r], (l & 48) | ro[r], 64);
        if (lc == 0) {
            out[BATCH + grow] = pv + pbr[r];
            out[2 * BATCH + grow] = 1.f / (1.f + expf(-(tv + tbr[r])));
        }
    }
    __syncthreads();   // lS/pW/tW reads done; W0 staged (vmcnt drained)

    // ---- stage expert option-1 -> wbuf1 (drained at iter-0's end barrier) ----
#pragma unroll
    for (int i = 0; i < 5; ++i) {
        int f = w * 5 + i;
        __builtin_amdgcn_global_load_lds((const void*)(expw + 10240 + f * 512 + l * 8),
                                         (void*)(lmem + L_WB1 + f * 1024), 16, 0, 0);
    }

    // ---- expert option loop (fully unrolled; 1 barrier per option) ----
    float* lL = (float*)(lmem + L_LL);
#pragma unroll
    for (int o = 0; o < N_OPT; ++o) {
        const char* wb = lmem + ((o & 1) ? L_WB1 : L_WB0);

        f32x4 acc[4] = {{0,0,0,0},{0,0,0,0},{0,0,0,0},{0,0,0,0}};
#pragma unroll
        for (int ks = 0; ks < 4; ++ks) {
#pragma unroll
            for (int nn = 0; nn < 4; ++nn) {
                short8 b = *reinterpret_cast<const short8*>(wb + (ks * 4 + nn) * 1024 + l16);
                acc[nn] = MFMA(a4[ks], b, acc[nn]);
            }
        }
#pragma unroll
        for (int nn = 0; nn < 4; ++nn) {
            float bias = ob1[o * HID + nn * 16 + lc];
#pragma unroll
            for (int r = 0; r < 4; ++r) {
                if (ro[r] == o) {
                    u16 ev = bf(fmaxf(acc[nn][r] + bias, 0.f));
                    int ad = L_E + w * 2048 + (nn >> 1) * 1024
                           + (((((nn & 1) * 2 + (lc >> 3)) * 16) + 4 * lg + r) << 4) + ((lc & 7) << 1);
                    *(u16*)(lmem + ad) = ev;
                }
            }
        }
        // own-wave lE write->read: LDS pipe order suffices (stale rows predicated out)
        short8 a2[2];
#pragma unroll
        for (int ks = 0; ks < 2; ++ks)
            a2[ks] = *reinterpret_cast<const short8*>(lmem + L_E + w * 2048 + ks * 1024 + l16);
        f32x4 accl[2] = {{0,0,0,0},{0,0,0,0}};
#pragma unroll
        for (int ks = 0; ks < 2; ++ks) {
#pragma unroll
            for (int nn = 0; nn < 2; ++nn) {
                short8 b = *reinterpret_cast<const short8*>(wb + (16 + ks * 2 + nn) * 1024 + l16);
                accl[nn] = MFMA(a2[ks], b, accl[nn]);
            }
        }
#pragma unroll
        for (int nn = 0; nn < 2; ++nn) {
            int col = nn * 16 + lc;
            if (col < ACT_N) {
                float bias = ob2[o * ACT_N + col];
#pragma unroll
                for (int r = 0; r < 4; ++r)
                    if (ro[r] == o) lL[(16 * w + 4 * lg + r) * 19 + col] = accl[nn][r] + bias;
            }
        }
        __syncthreads();   // wb reads done (all waves); drains W(o+1)'s staging
        if (o < 6) {       // stage W(o+2) into the buffer just freed
            char* db = lmem + ((o & 1) ? L_WB1 : L_WB0);
#pragma unroll
            for (int i = 0; i < 5; ++i) {
                int f = w * 5 + i;
                __builtin_amdgcn_global_load_lds((const void*)(expw + (o + 2) * 10240 + f * 512 + l * 8),
                                                 (void*)(db + f * 1024), 16, 0, 0);
            }
        }
    }

    // ---- log-softmax + gather(act): 4 lanes per row ----
    {
        int row = tid >> 2, q = tid & 3;
        const float* lr = lL + row * 19;
        float mx = -1e30f;
        for (int a = q; a < ACT_N; a += 4) mx = fmaxf(mx, lr[a]);
        mx = fmaxf(mx, __shfl_xor(mx, 1, 64));
        mx = fmaxf(mx, __shfl_xor(mx, 2, 64));
        float s = 0.f;
        for (int a = q; a < ACT_N; a += 4) s += expf(lr[a] - mx);
        s += __shfl_xor(s, 1, 64);
        s += __shfl_xor(s, 2, 64);
        if (q == 0) out[tile * 64 + row] = (lr[myact] - mx) - logf(s);
    }
}

// ---------------------------------------------------------------------------
extern "C" void kernel_launch(void* const* d_in, const int* in_sizes, int n_in,
                              void* d_out, int out_size, void* d_ws, size_t ws_size,
                              hipStream_t stream) {
    const float* obs = (const float*)d_in[0];
    const int*   act = (const int*)d_in[1];
    const int*   opt = (const int*)d_in[2];
    const float* fW1 = (const float*)d_in[3];
    const float* fb1 = (const float*)d_in[4];
    const float* fW2 = (const float*)d_in[5];
    const float* fb2 = (const float*)d_in[6];
    const float* pW  = (const float*)d_in[7];
    const float* pb  = (const float*)d_in[8];
    const float* tW  = (const float*)d_in[9];
    const float* tb  = (const float*)d_in[10];
    const float* oW1 = (const float*)d_in[11];
    const float* ob1 = (const float*)d_in[12];
    const float* oW2 = (const float*)d_in[13];
    const float* ob2 = (const float*)d_in[14];
    float* out = (float*)d_out;

    u16* wsu = (u16*)d_ws;
    const u16* trkw = wsu;
    const u16* expw = wsu + TRK_U16;

    k_prep<<<64, 256, 0, stream>>>(fW1, fW2, pW, tW, oW1, oW2, wsu);
    k_fused<<<BATCH / 64, 256, 0, stream>>>(obs, opt, act, trkw, expw,
                                            fb1, fb2, pb, tb, ob1, ob2, out);
}

// Round 13
// 118.322 us; speedup vs baseline: 1.2921x; 1.0097x over previous
//
#include <hip/hip_runtime.h>
#include <hip/hip_bf16.h>
#include <math.h>

#define OBS_DIM 256
#define FEAT 128
#define HID 64
#define N_OPT 8
#define ACT_N 18
#define BATCH 32768

typedef unsigned short u16;
typedef unsigned int u32;
typedef __attribute__((ext_vector_type(8))) short short8;
typedef __attribute__((ext_vector_type(4))) float f32x4;

#define MFMA(a, b, c) __builtin_amdgcn_mfma_f32_16x16x32_bf16((a), (b), (c), 0, 0, 0)

union frag_u { u32 u[4]; short8 s; };

// ---- ws layout (u16 units), ALL weights pre-permuted frag-major by k_prep:
//   trkw: 56 frags x 512 u16 (fW1 f0-31, fW2 f32-47, pW f48-51, tW f52-55)
//   expw: 8 options x 20 frags x 512 (per option: W1 f0-15, W2 f16-19)
#define TRK_U16 28672
#define EXP_U16 81920

// ---- LDS arena 54016 B -> 3 blocks/CU (163840/54016 = 3.03). Aliasing:
//  [0,32768)      fW1 frags 0-31            (stage .. L1)
//  [0,16384)      fW2 frags (16)            (post-L1a .. L2)
//  [16384,32768)  lS per-wave 4KB scratch   (post-L2, own-wave transpose)
//  [32768,40960)  lH per-wave 2KB           (L1 .. L2)
//  [0,20480)      wbuf0 / [20480,40960) wbuf1   (expert dbuf)
//  [40960,49152)  lE per-wave 2KB           (expert loop)
//  [49152,54016)  lL logits f32 [64][19]
#define L_LH  32768
#define L_LS  16384
#define L_WB0 0
#define L_WB1 20480
#define L_E   40960
#define L_LL  49152
#define ARENA 54016

__device__ __forceinline__ u16 bf(float x) {  // RNE f32->bf16
    u32 u = __float_as_uint(x);
    return (u16)((u + 0x7fffu + ((u >> 16) & 1u)) >> 16);
}
__device__ __forceinline__ u32 cvtpk(float lo, float hi) {  // 2xf32 -> packed 2xbf16 (RNE)
    u32 r;
    asm("v_cvt_pk_bf16_f32 %0, %1, %2" : "=v"(r) : "v"(lo), "v"(hi));
    return r;
}

// ---------------------------------------------------------------------------
// K0: build frag-major bf16 weight images (identical to round 7 — verified).
// ---------------------------------------------------------------------------
__global__ __launch_bounds__(256) void k_prep(
    const float* __restrict__ fW1, const float* __restrict__ fW2,
    const float* __restrict__ pW,  const float* __restrict__ tW,
    const float* __restrict__ oW1, const float* __restrict__ oW2,
    u16* __restrict__ dst)
{
    int gid = blockIdx.x * 256 + threadIdx.x;
    int stride = gridDim.x * 256;
    for (int i = gid; i < TRK_U16 + EXP_U16; i += stride) {
        float v;
        if (i < TRK_U16) {
            int f = i >> 9, l = (i >> 3) & 63, j = i & 7;
            int lc = l & 15, lg = l >> 4;
            if (f < 32) {
                int ks = f >> 2, nn = f & 3;
                v = fW1[(nn * 16 + lc) * 256 + ks * 32 + lg * 8 + j];
            } else if (f < 48) {
                int f2 = f - 32, ks = f2 >> 3, nn = f2 & 7;
                v = fW2[(nn * 16 + lc) * 64 + ks * 32 + lg * 8 + j];
            } else if (f < 52) {
                int ks = f - 48;
                v = (lc < N_OPT) ? pW[lc * 128 + ks * 32 + lg * 8 + j] : 0.f;
            } else {
                int ks = f - 52;
                v = (lc < N_OPT) ? tW[lc * 128 + ks * 32 + lg * 8 + j] : 0.f;
            }
        } else {
            int t = i - TRK_U16;
            int o = t / 10240, t2 = t - o * 10240;
            int f = t2 >> 9, l = (t2 >> 3) & 63, j = t2 & 7;
            int lc = l & 15, lg = l >> 4;
            if (f < 16) {
                int ks = f >> 2, nn = f & 3;
                v = oW1[o * 8192 + (nn * 16 + lc) * 128 + ks * 32 + lg * 8 + j];
            } else {
                int f2 = f - 16, ks = f2 >> 1, nn = f2 & 1;
                int row = nn * 16 + lc;
                v = (row < ACT_N) ? oW2[o * (ACT_N * 64) + row * 64 + ks * 32 + lg * 8 + j] : 0.f;
            }
        }
        dst[i] = bf(v);
    }
}

// ---------------------------------------------------------------------------
// K1: fused, 54KB LDS -> 3 blocks/CU. fW1 staged once; fW2 reuses fW1.a's
// region after the mid-L1 barrier; heads' B-frags live in registers.
// FIX vs round 7: expert-dbuf prefetch destination was inverted
// ((o&1)?WB0:WB1) — it clobbered W(o+1) before its reads. Correct selector
// stages W(o+2) into the buffer just consumed at iteration o.
// ---------------------------------------------------------------------------
__global__ __launch_bounds__(256, 3) void k_fused(
    const float* __restrict__ obs, const int* __restrict__ opt,
    const int* __restrict__ act,
    const u16* __restrict__ trkw, const u16* __restrict__ expw,
    const float* __restrict__ fb1, const float* __restrict__ fb2,
    const float* __restrict__ pb,  const float* __restrict__ tb,
    const float* __restrict__ ob1, const float* __restrict__ ob2,
    float* __restrict__ out)
{
    __shared__ char lmem[ARENA];
    const int tid = threadIdx.x;
    const int tile = blockIdx.x;
    const int w = tid >> 6, l = tid & 63, lg = l >> 4, lc = l & 15;
    const int l16 = l * 16;

    // ---- stage fW1 (32 frags, 8/wave) ----
#pragma unroll
    for (int i = 0; i < 8; ++i) {
        int f = w * 8 + i;
        __builtin_amdgcn_global_load_lds((const void*)(trkw + f * 512 + l * 8),
                                         (void*)(lmem + f * 1024), 16, 0, 0);
    }

    // ---- obs -> 8 A-frags in registers (two 32-VGPR batches) ----
    const float* orow = obs + (size_t)(tile * 64 + 16 * w + lc) * OBS_DIM + lg * 8;
    frag_u a1[8];
    {
        float4 of[8];
#pragma unroll
        for (int ks = 0; ks < 4; ++ks) {
            of[2 * ks]     = *reinterpret_cast<const float4*>(orow + ks * 32);
            of[2 * ks + 1] = *reinterpret_cast<const float4*>(orow + ks * 32 + 4);
        }
#pragma unroll
        for (int ks = 0; ks < 4; ++ks) {
            a1[ks].u[0] = cvtpk(of[2 * ks].x,     of[2 * ks].y);
            a1[ks].u[1] = cvtpk(of[2 * ks].z,     of[2 * ks].w);
            a1[ks].u[2] = cvtpk(of[2 * ks + 1].x, of[2 * ks + 1].y);
            a1[ks].u[3] = cvtpk(of[2 * ks + 1].z, of[2 * ks + 1].w);
        }
#pragma unroll
        for (int ks = 4; ks < 8; ++ks) {
            of[2 * (ks - 4)]     = *reinterpret_cast<const float4*>(orow + ks * 32);
            of[2 * (ks - 4) + 1] = *reinterpret_cast<const float4*>(orow + ks * 32 + 4);
        }
#pragma unroll
        for (int ks = 4; ks < 8; ++ks) {
            a1[ks].u[0] = cvtpk(of[2 * (ks - 4)].x,     of[2 * (ks - 4)].y);
            a1[ks].u[1] = cvtpk(of[2 * (ks - 4)].z,     of[2 * (ks - 4)].w);
            a1[ks].u[2] = cvtpk(of[2 * (ks - 4) + 1].x, of[2 * (ks - 4) + 1].y);
            a1[ks].u[3] = cvtpk(of[2 * (ks - 4) + 1].z, of[2 * (ks - 4) + 1].w);
        }
    }
    int ro[4];
#pragma unroll
    for (int r = 0; r < 4; ++r) ro[r] = opt[tile * 64 + 16 * w + 4 * lg + r];
    int myact = act[tile * 64 + (tid >> 2)];
    float pbr[4], tbr[4];
#pragma unroll
    for (int r = 0; r < 4; ++r) { pbr[r] = pb[ro[r]]; tbr[r] = tb[ro[r]]; }
    float fb1v[4], fb2v[8];
#pragma unroll
    for (int nn = 0; nn < 4; ++nn) fb1v[nn] = fb1[nn * 16 + lc];
#pragma unroll
    for (int nn = 0; nn < 8; ++nn) fb2v[nn] = fb2[nn * 16 + lc];

    __syncthreads();   // b1: fW1 staged (vmcnt drained)

    // ---- trunk L1, first half (ks 0-3, frags 0-15) ----
    f32x4 acc1[4] = {{0,0,0,0},{0,0,0,0},{0,0,0,0},{0,0,0,0}};
#pragma unroll
    for (int ks = 0; ks < 4; ++ks) {
#pragma unroll
        for (int nn = 0; nn < 4; ++nn) {
            short8 b = *reinterpret_cast<const short8*>(lmem + (ks * 4 + nn) * 1024 + l16);
            acc1[nn] = MFMA(a1[ks].s, b, acc1[nn]);
        }
    }
    __syncthreads();   // b2: all waves done with fW1.a region

    // stage fW2 (16 frags, 4/wave) into [0,16K); head B-frags -> registers
#pragma unroll
    for (int i = 0; i < 4; ++i) {
        int f = w * 4 + i;
        __builtin_amdgcn_global_load_lds((const void*)(trkw + (32 + f) * 512 + l * 8),
                                         (void*)(lmem + f * 1024), 16, 0, 0);
    }
    short8 bpr[4], btr[4];
#pragma unroll
    for (int ks = 0; ks < 4; ++ks) {
        bpr[ks] = *reinterpret_cast<const short8*>(trkw + (48 + ks) * 512 + l * 8);
        btr[ks] = *reinterpret_cast<const short8*>(trkw + (52 + ks) * 512 + l * 8);
    }

    // ---- trunk L1, second half (ks 4-7, frags 16-31) ----
#pragma unroll
    for (int ks = 4; ks < 8; ++ks) {
#pragma unroll
        for (int nn = 0; nn < 4; ++nn) {
            short8 b = *reinterpret_cast<const short8*>(lmem + (ks * 4 + nn) * 1024 + l16);
            acc1[nn] = MFMA(a1[ks].s, b, acc1[nn]);
        }
    }
    // epilogue -> lH (own-wave region, lgkm ordering suffices)
#pragma unroll
    for (int nn = 0; nn < 4; ++nn) {
#pragma unroll
        for (int r = 0; r < 4; ++r) {
            u16 hv = bf(fmaxf(acc1[nn][r] + fb1v[nn], 0.f));
            int ad = L_LH + w * 2048 + (nn >> 1) * 1024
                   + (((((nn & 1) * 2 + (lc >> 3)) * 16) + 4 * lg + r) << 4) + ((lc & 7) << 1);
            *(u16*)(lmem + ad) = hv;
        }
    }
    __syncthreads();   // b3: drains fW2 staging; fW1.b region now globally dead

    // ---- trunk L2 (b from fW2 frags at [0,16K)) ----
    f32x4 acc2[8];
#pragma unroll
    for (int nn = 0; nn < 8; ++nn) acc2[nn] = (f32x4){0,0,0,0};
#pragma unroll
    for (int ks = 0; ks < 2; ++ks) {
        short8 a = *reinterpret_cast<const short8*>(lmem + L_LH + w * 2048 + ks * 1024 + l16);
#pragma unroll
        for (int nn = 0; nn < 8; ++nn) {
            short8 b = *reinterpret_cast<const short8*>(lmem + (ks * 8 + nn) * 1024 + l16);
            acc2[nn] = MFMA(a, b, acc2[nn]);
        }
    }

    // ---- state transpose via per-wave 4KB scratch (dead fW1.b region) ----
#pragma unroll
    for (int nn = 0; nn < 8; ++nn) {
#pragma unroll
        for (int r = 0; r < 4; ++r) {
            u16 sv = bf(fmaxf(acc2[nn][r] + fb2v[nn], 0.f));
            int ad = L_LS + w * 4096 + (nn >> 1) * 1024
                   + (((((nn & 1) * 2 + (lc >> 3)) * 16) + 4 * lg + r) << 4) + ((lc & 7) << 1);
            *(u16*)(lmem + ad) = sv;
        }
    }
    short8 a4[4];
#pragma unroll
    for (int ks = 0; ks < 4; ++ks)
        a4[ks] = *reinterpret_cast<const short8*>(lmem + L_LS + w * 4096 + ks * 1024 + l16);

    __syncthreads();   // b4: fW2 reads + own lS reads done -> wbuf regions free

    // ---- issue expert options 0,1 (20 frags each, 5/wave) ----
#pragma unroll
    for (int i = 0; i < 5; ++i) {
        int f = w * 5 + i;
        __builtin_amdgcn_global_load_lds((const void*)(expw + f * 512 + l * 8),
                                         (void*)(lmem + L_WB0 + f * 1024), 16, 0, 0);
        __builtin_amdgcn_global_load_lds((const void*)(expw + 10240 + f * 512 + l * 8),
                                         (void*)(lmem + L_WB1 + f * 1024), 16, 0, 0);
    }

    // ---- heads (B in registers) — covers part of the wbuf staging latency ----
    {
        f32x4 accP = {0,0,0,0}, accT = {0,0,0,0};
#pragma unroll
        for (int ks = 0; ks < 4; ++ks) {
            accP = MFMA(a4[ks], bpr[ks], accP);
            accT = MFMA(a4[ks], btr[ks], accT);
        }
#pragma unroll
        for (int r = 0; r < 4; ++r) {
            int grow = tile * 64 + 16 * w + 4 * lg + r;
            float pv = __shfl(accP[r], (l & 48) | ro[r], 64);
            float tv = __shfl(accT[r], (l & 48) | ro[r], 64);
            if (lc == 0) {
                out[BATCH + grow] = pv + pbr[r];
                out[2 * BATCH + grow] = 1.f / (1.f + expf(-(tv + tbr[r])));
            }
        }
    }
    __syncthreads();   // b5: drains wbuf0/wbuf1 staging

    // ---- expert option loop ----
    float* lL = (float*)(lmem + L_LL);
#pragma unroll
    for (int o = 0; o < N_OPT; ++o) {
        const char* wb = lmem + ((o & 1) ? L_WB1 : L_WB0);

        f32x4 acc[4] = {{0,0,0,0},{0,0,0,0},{0,0,0,0},{0,0,0,0}};
#pragma unroll
        for (int ks = 0; ks < 4; ++ks) {
#pragma unroll
            for (int nn = 0; nn < 4; ++nn) {
                short8 b = *reinterpret_cast<const short8*>(wb + (ks * 4 + nn) * 1024 + l16);
                acc[nn] = MFMA(a4[ks], b, acc[nn]);
            }
        }
#pragma unroll
        for (int nn = 0; nn < 4; ++nn) {
            float bias = ob1[o * HID + nn * 16 + lc];
#pragma unroll
            for (int r = 0; r < 4; ++r) {
                if (ro[r] == o) {
                    u16 ev = bf(fmaxf(acc[nn][r] + bias, 0.f));
                    int ad = L_E + w * 2048 + (nn >> 1) * 1024
                           + (((((nn & 1) * 2 + (lc >> 3)) * 16) + 4 * lg + r) << 4) + ((lc & 7) << 1);
                    *(u16*)(lmem + ad) = ev;
                }
            }
        }
        short8 a2[2];
#pragma unroll
        for (int ks = 0; ks < 2; ++ks)
            a2[ks] = *reinterpret_cast<const short8*>(lmem + L_E + w * 2048 + ks * 1024 + l16);
        f32x4 accl[2] = {{0,0,0,0},{0,0,0,0}};
#pragma unroll
        for (int ks = 0; ks < 2; ++ks) {
#pragma unroll
            for (int nn = 0; nn < 2; ++nn) {
                short8 b = *reinterpret_cast<const short8*>(wb + (16 + ks * 2 + nn) * 1024 + l16);
                accl[nn] = MFMA(a2[ks], b, accl[nn]);
            }
        }
#pragma unroll
        for (int nn = 0; nn < 2; ++nn) {
            int col = nn * 16 + lc;
            if (col < ACT_N) {
                float bias = ob2[o * ACT_N + col];
#pragma unroll
                for (int r = 0; r < 4; ++r)
                    if (ro[r] == o) lL[(16 * w + 4 * lg + r) * 19 + col] = accl[nn][r] + bias;
            }
        }
        if (o < 7) {
            __syncthreads();   // wb reads done everywhere; drains W(o+1)'s staging
            if (o < 6) {
                // FIX: stage W(o+2) into the buffer just consumed at this
                // iteration (wb's region), NOT the one holding W(o+1).
                char* db = lmem + ((o & 1) ? L_WB1 : L_WB0);
#pragma unroll
                for (int i = 0; i < 5; ++i) {
                    int f = w * 5 + i;
                    __builtin_amdgcn_global_load_lds(
                        (const void*)(expw + (o + 2) * 10240 + f * 512 + l * 8),
                        (void*)(db + f * 1024), 16, 0, 0);
                }
            }
        }
    }

    // ---- log-softmax + gather(act): rows are own-wave -> no barrier ----
    {
        int row = tid >> 2, q = tid & 3;
        const float* lr = lL + row * 19;
        float mx = -1e30f;
        for (int a = q; a < ACT_N; a += 4) mx = fmaxf(mx, lr[a]);
        mx = fmaxf(mx, __shfl_xor(mx, 1, 64));
        mx = fmaxf(mx, __shfl_xor(mx, 2, 64));
        float s = 0.f;
        for (int a = q; a < ACT_N; a += 4) s += expf(lr[a] - mx);
        s += __shfl_xor(s, 1, 64);
        s += __shfl_xor(s, 2, 64);
        if (q == 0) out[tile * 64 + row] = (lr[myact] - mx) - logf(s);
    }
}

// ---------------------------------------------------------------------------
extern "C" void kernel_launch(void* const* d_in, const int* in_sizes, int n_in,
                              void* d_out, int out_size, void* d_ws, size_t ws_size,
                              hipStream_t stream) {
    const float* obs = (const float*)d_in[0];
    const int*   act = (const int*)d_in[1];
    const int*   opt = (const int*)d_in[2];
    const float* fW1 = (const float*)d_in[3];
    const float* fb1 = (const float*)d_in[4];
    const float* fW2 = (const float*)d_in[5];
    const float* fb2 = (const float*)d_in[6];
    const float* pW  = (const float*)d_in[7];
    const float* pb  = (const float*)d_in[8];
    const float* tW  = (const float*)d_in[9];
    const float* tb  = (const float*)d_in[10];
    const float* oW1 = (const float*)d_in[11];
    const float* ob1 = (const float*)d_in[12];
    const float* oW2 = (const float*)d_in[13];
    const float* ob2 = (const float*)d_in[14];
    float* out = (float*)d_out;

    u16* wsu = (u16*)d_ws;
    const u16* trkw = wsu;
    const u16* expw = wsu + TRK_U16;

    k_prep<<<64, 256, 0, stream>>>(fW1, fW2, pW, tW, oW1, oW2, wsu);
    k_fused<<<BATCH / 64, 256, 0, stream>>>(obs, opt, act, trkw, expw,
                                            fb1, fb2, pb, tb, ob1, ob2, out);
}